// Round 9
// baseline (112.339 us; speedup 1.0000x reference)
//
#include <hip/hip_runtime.h>
#include <math.h>

#define D_MODEL 1024
#define HEAD 64
#define BATCH 4
#define SEQ 2048
#define M_TOT (BATCH*SEQ)   // 8192

typedef short short8 __attribute__((ext_vector_type(8)));
typedef float f32x4 __attribute__((ext_vector_type(4)));
typedef unsigned short ushort_t;

__device__ __forceinline__ unsigned short f2bf(float x) {       // round-to-nearest
    union { float f; unsigned u; } v; v.f = x;
    unsigned r = (v.u + 0x7FFFu + ((v.u >> 16) & 1u)) >> 16;
    return (unsigned short)r;
}
__device__ __forceinline__ unsigned short f2bf_trunc(float x) { // truncate mantissa
    union { float f; unsigned u; } v; v.f = x;
    return (unsigned short)(v.u >> 16);
}
__device__ __forceinline__ float bf2f(unsigned short h) {
    union { unsigned u; float f; } v; v.u = ((unsigned)h) << 16;
    return v.f;
}

// ---------------- W split prep: fp32 [1024][64]x3 -> bf16 hi/lo frag layout --
// Wf[((ks*12 + nt)*64 + l)*8 + e], nt: 0-3=Q, 4-7=K, 8-11=V.
// lane l=(c,g): col = (nt&3)*16 + c, k = 32*ks + 8*g + e.
__global__ __launch_bounds__(256) void wsplit_kernel(
    const float* __restrict__ wq, const float* __restrict__ wk,
    const float* __restrict__ wv,
    ushort_t* __restrict__ Wfhi, ushort_t* __restrict__ Wflo)
{
    int tid = blockIdx.x * 256 + threadIdx.x;      // 0..24575
    int l = tid & 63;
    int c = l & 15, g = l >> 4;
    int rest = tid >> 6;
    int nt = rest % 12, ks = rest / 12;
    const float* W = (nt < 4) ? wq : ((nt < 8) ? wk : wv);
    int colm = ((nt & 3) * 16) + c;
    short8 hi, lo;
#pragma unroll
    for (int e = 0; e < 8; ++e) {
        float v = W[(size_t)(32 * ks + 8 * g + e) * HEAD + colm];
        unsigned short h = f2bf_trunc(v);
        hi[e] = (short)h;
        lo[e] = (short)f2bf(v - bf2f(h));
    }
    *(short8*)&Wfhi[(size_t)tid * 8] = hi;
    *(short8*)&Wflo[(size_t)tid * 8] = lo;
}

// ---------------- QKV projection (MFMA split-bf16, 1 wave per 16-col job) --
// Job = (mt, nt): 16-row m-tile x one 16-col tile. nt: 0-3=Q, 4-7=K, 8-11=V.
// 6144 jobs = 24 waves/CU. x converted fp32->bf16 hi/lo on the fly.
__global__ __launch_bounds__(256) void proj_kernel(
    const float* __restrict__ x,
    const ushort_t* __restrict__ Wfhi, const ushort_t* __restrict__ Wflo,
    const float* __restrict__ bq, const float* __restrict__ bk,
    const float* __restrict__ bv,
    ushort_t* __restrict__ Qhi, ushort_t* __restrict__ Qlo,
    ushort_t* __restrict__ Khi, ushort_t* __restrict__ Klo,
    ushort_t* __restrict__ Vt)
{
    __shared__ float ld[4][16][17];
    const int t = threadIdx.x;
    const int w = t >> 6;
    const int l = t & 63;
    const int c = l & 15, g = l >> 4;
    const int job = blockIdx.x * 4 + w;
    const int mt = job / 12;
    const int nt = job - mt * 12;
    const int m0 = mt * 16;

    f32x4 acc = (f32x4)0.0f;
    const float* xrow = &x[(size_t)(m0 + c) * D_MODEL + 8 * g];
    const size_t wlane = (size_t)(nt * 64 + l) * 8;

#pragma unroll 4
    for (int ks = 0; ks < 32; ++ks) {
        const float* xp = xrow + 32 * ks;
        float4 a = *(const float4*)xp;
        float4 b2 = *(const float4*)(xp + 4);
        float xs[8] = {a.x, a.y, a.z, a.w, b2.x, b2.y, b2.z, b2.w};
        short8 xh, xl;
#pragma unroll
        for (int e = 0; e < 8; ++e) {
            unsigned short h = f2bf_trunc(xs[e]);
            xh[e] = (short)h;
            xl[e] = (short)f2bf(xs[e] - bf2f(h));
        }
        const size_t wo = wlane + (size_t)ks * 6144;
        short8 wh = *(const short8*)&Wfhi[wo];
        short8 wl_ = *(const short8*)&Wflo[wo];
        acc = __builtin_amdgcn_mfma_f32_16x16x32_bf16(xh, wh, acc, 0, 0, 0);
        acc = __builtin_amdgcn_mfma_f32_16x16x32_bf16(xl, wh, acc, 0, 0, 0);
        acc = __builtin_amdgcn_mfma_f32_16x16x32_bf16(xh, wl_, acc, 0, 0, 0);
    }

    // stage D tile: lane holds rows 4g+r of col c
#pragma unroll
    for (int r = 0; r < 4; ++r) ld[w][4 * g + r][c] = acc[r];
    // same-wave LDS region: no barrier needed

    const int b = m0 >> 11;
    const int s0 = m0 & 2047;
    const int col16 = (nt & 3) * 16;

    if (nt < 8) {
        // Q or K: row = l>>2, 4 cols at (l&3)*4
        const int row = l >> 2, cc4 = (l & 3) * 4;
        const float* bias = (nt < 4) ? bq : bk;
        const float scale = (nt < 4) ? 8.0f : 1.0f;
        ushort_t* Dhi = (nt < 4) ? Qhi : Khi;
        ushort_t* Dlo = (nt < 4) ? Qlo : Klo;
        unsigned hu[2] = {0, 0}, lu[2] = {0, 0};
#pragma unroll
        for (int i = 0; i < 4; ++i) {
            float v = (ld[w][row][cc4 + i] + bias[col16 + cc4 + i]) * scale;
            unsigned short h = f2bf_trunc(v);
            unsigned short lo = f2bf(v - bf2f(h));
            hu[i >> 1] |= ((unsigned)h) << ((i & 1) * 16);
            lu[i >> 1] |= ((unsigned)lo) << ((i & 1) * 16);
        }
        size_t off = (size_t)(m0 + row) * HEAD + col16 + cc4;
        *(uint2*)&Dhi[off] = make_uint2(hu[0], hu[1]);
        *(uint2*)&Dlo[off] = make_uint2(lu[0], lu[1]);
    } else {
        // V -> Vt[b][d][s]: d_local = l>>2, 4 s at (l&3)*4
        const int dl = l >> 2, sg = (l & 3) * 4;
        const float bb = bv[col16 + dl];
        unsigned vu[2] = {0, 0};
#pragma unroll
        for (int i = 0; i < 4; ++i) {
            unsigned short v = f2bf(ld[w][sg + i][dl] + bb);
            vu[i >> 1] |= ((unsigned)v) << ((i & 1) * 16);
        }
        *(uint2*)&Vt[((size_t)b * HEAD + col16 + dl) * SEQ + s0 + sg] =
            make_uint2(vu[0], vu[1]);
    }
}

// ---------------- Flash causal attention (MFMA, split-KV, 8 waves) ------
#define NW 8
#define CHUNK 16
#define PSTR 88   // Plds stride in shorts: 176B = 11*16B (aligned, ~2-way banks)

__global__ __launch_bounds__(512) void attn_kernel(
    const ushort_t* __restrict__ Qhi, const ushort_t* __restrict__ Qlo,
    const ushort_t* __restrict__ Khi, const ushort_t* __restrict__ Klo,
    const ushort_t* __restrict__ Vt, float* __restrict__ out)
{
    __shared__ float Po[NW][CHUNK][68];
    __shared__ float Pm[NW][CHUNK];
    __shared__ float Pl[NW][CHUNK];
    __shared__ __align__(16) ushort_t Plds[NW][CHUNK][PSTR];

    const int t = threadIdx.x;
    const int w = t >> 6;
    const int l = t & 63;
    const int b = blockIdx.y;
    const int chunk = (int)gridDim.x - 1 - (int)blockIdx.x;  // biggest first
    const int q0 = chunk * CHUNK;
    const int c = l & 15;
    const int g = l >> 4;

    short8 qhi[2], qlo[2];
    {
        const ushort_t* qbase = &Qhi[(size_t)(b * SEQ + q0 + c) * HEAD];
        const ushort_t* qbasel = &Qlo[(size_t)(b * SEQ + q0 + c) * HEAD];
#pragma unroll
        for (int dc = 0; dc < 2; ++dc) {
            qhi[dc] = *(const short8*)&qbase[dc * 32 + 8 * g];
            qlo[dc] = *(const short8*)&qbasel[dc * 32 + 8 * g];
        }
    }

    f32x4 acc[4];
#pragma unroll
    for (int dt = 0; dt < 4; ++dt) acc[dt] = (f32x4)0.0f;
    float mrun = -1e30f, lsum = 0.f;

    const int ntiles = (q0 + CHUNK + 63) >> 6;
#pragma unroll 1
    for (int tile = w; tile < ntiles; tile += NW) {
        const int c0 = tile * 64;
        int nlive = ((q0 + 15 - c0) >> 4) + 1;
        nlive = nlive > 4 ? 4 : nlive;

        float sc[4][4];
        float pv[4][4];
#pragma unroll
        for (int t4 = 0; t4 < 4; ++t4)
#pragma unroll
            for (int r = 0; r < 4; ++r) pv[t4][r] = 0.f;

        float tmax = -1e30f;
#pragma unroll
        for (int t4 = 0; t4 < 4; ++t4) {
            if (t4 < nlive) {
                f32x4 st = (f32x4)0.0f;
                const size_t krow = (size_t)(b * SEQ + c0 + 16 * t4 + c) * HEAD;
#pragma unroll
                for (int dc = 0; dc < 2; ++dc) {
                    short8 khi = *(const short8*)&Khi[krow + dc * 32 + 8 * g];
                    short8 klo = *(const short8*)&Klo[krow + dc * 32 + 8 * g];
                    st = __builtin_amdgcn_mfma_f32_16x16x32_bf16(khi, qhi[dc], st, 0, 0, 0);
                    st = __builtin_amdgcn_mfma_f32_16x16x32_bf16(khi, qlo[dc], st, 0, 0, 0);
                    st = __builtin_amdgcn_mfma_f32_16x16x32_bf16(klo, qhi[dc], st, 0, 0, 0);
                }
#pragma unroll
                for (int r = 0; r < 4; ++r) {
                    int kv = c0 + 16 * t4 + 4 * g + r;
                    float s = (kv <= q0 + c) ? st[r] : -1e30f;
                    sc[t4][r] = s;
                    tmax = fmaxf(tmax, s);
                }
            }
        }
        tmax = fmaxf(tmax, __shfl_xor(tmax, 16));
        tmax = fmaxf(tmax, __shfl_xor(tmax, 32));
        float newm = fmaxf(mrun, tmax);
        float corr = __expf(mrun - newm);
        mrun = newm;

        float psum = 0.f;
#pragma unroll
        for (int t4 = 0; t4 < 4; ++t4) {
            if (t4 < nlive) {
#pragma unroll
                for (int r = 0; r < 4; ++r) {
                    float pp = __expf(sc[t4][r] - newm);
                    pv[t4][r] = pp;
                    psum += pp;
                }
            }
        }
        psum += __shfl_xor(psum, 16);
        psum += __shfl_xor(psum, 32);
        lsum = lsum * corr + psum;

#pragma unroll
        for (int r = 0; r < 4; ++r) {
            float cq = __shfl(corr, 4 * g + r);
#pragma unroll
            for (int dt = 0; dt < 4; ++dt) acc[dt][r] *= cq;
        }

#pragma unroll
        for (int t4 = 0; t4 < 4; ++t4) {
            uint2 u;
            u.x = (unsigned)f2bf(pv[t4][0]) | ((unsigned)f2bf(pv[t4][1]) << 16);
            u.y = (unsigned)f2bf(pv[t4][2]) | ((unsigned)f2bf(pv[t4][3]) << 16);
            *(uint2*)&Plds[w][c][16 * t4 + 4 * g] = u;
        }

        const int nkvc = (nlive + 1) >> 1;
#pragma unroll
        for (int kvc = 0; kvc < 2; ++kvc) {
            if (kvc < nkvc) {
                short8 pf = *(short8*)&Plds[w][c][kvc * 32 + 8 * g];
#pragma unroll
                for (int dt = 0; dt < 4; ++dt) {
                    const ushort_t* vp =
                        &Vt[((size_t)(b * HEAD) + 16 * dt + c) * SEQ + c0 + kvc * 32 + 8 * g];
                    short8 vf = *(const short8*)vp;
                    acc[dt] = __builtin_amdgcn_mfma_f32_16x16x32_bf16(pf, vf, acc[dt], 0, 0, 0);
                }
            }
        }
    }

    if (g == 0) { Pm[w][c] = mrun; Pl[w][c] = lsum; }
#pragma unroll
    for (int dt = 0; dt < 4; ++dt)
#pragma unroll
        for (int r = 0; r < 4; ++r)
            Po[w][4 * g + r][16 * dt + c] = acc[dt][r];
    __syncthreads();

    if (t < 256) {
        const int mr = t >> 4;
        const int md = (t & 15) * 4;
        float M = Pm[0][mr];
#pragma unroll
        for (int ww = 1; ww < NW; ++ww) M = fmaxf(M, Pm[ww][mr]);
        float L = 0.f;
        float4 O; O.x = O.y = O.z = O.w = 0.f;
#pragma unroll
        for (int ww = 0; ww < NW; ++ww) {
            float f = __expf(Pm[ww][mr] - M);
            L += f * Pl[ww][mr];
            float4 p = *(const float4*)&Po[ww][mr][md];
            O.x += f * p.x; O.y += f * p.y; O.z += f * p.z; O.w += f * p.w;
        }
        float inv = 1.0f / L;
        float4 res; res.x = O.x * inv; res.y = O.y * inv; res.z = O.z * inv; res.w = O.w * inv;
        *(float4*)&out[(size_t)(b * SEQ + q0 + mr) * HEAD + md] = res;
    }
}

extern "C" void kernel_launch(void* const* d_in, const int* in_sizes, int n_in,
                              void* d_out, int out_size, void* d_ws, size_t ws_size,
                              hipStream_t stream) {
    (void)in_sizes; (void)n_in; (void)out_size; (void)ws_size;
    const float* x  = (const float*)d_in[0];
    const float* wq = (const float*)d_in[1];
    const float* bq = (const float*)d_in[2];
    const float* wk = (const float*)d_in[3];
    const float* bk = (const float*)d_in[4];
    const float* wv = (const float*)d_in[5];
    const float* bv = (const float*)d_in[6];
    float* out = (float*)d_out;

    // workspace layout: 5.75 MB total (validated footprint)
    ushort_t* Wfhi = (ushort_t*)d_ws;                        // 384 KB
    ushort_t* Wflo = Wfhi + (size_t)D_MODEL * 192;           // 384 KB
    ushort_t* Qhi  = Wflo + (size_t)D_MODEL * 192;           // 1 MB each
    ushort_t* Qlo  = Qhi + (size_t)M_TOT * HEAD;
    ushort_t* Khi  = Qlo + (size_t)M_TOT * HEAD;
    ushort_t* Klo  = Khi + (size_t)M_TOT * HEAD;
    ushort_t* Vt   = Klo + (size_t)M_TOT * HEAD;             // [B][64][S], 1 MB

    hipLaunchKernelGGL(wsplit_kernel, dim3(96), dim3(256), 0, stream,
                       wq, wk, wv, Wfhi, Wflo);
    hipLaunchKernelGGL(proj_kernel, dim3(M_TOT / 16 * 12 / 4), dim3(256), 0, stream,
                       x, Wfhi, Wflo, bq, bk, bv, Qhi, Qlo, Khi, Klo, Vt);
    hipLaunchKernelGGL(attn_kernel, dim3(SEQ / CHUNK, BATCH), dim3(512), 0, stream,
                       Qhi, Qlo, Khi, Klo, Vt, out);
}

// Round 10
// 89.510 us; speedup vs baseline: 1.2550x; 1.2550x over previous
//
#include <hip/hip_runtime.h>
#include <math.h>

#define D_MODEL 1024
#define HEAD 64
#define BATCH 4
#define SEQ 2048
#define M_TOT (BATCH*SEQ)   // 8192

typedef short short8 __attribute__((ext_vector_type(8)));
typedef float f32x4 __attribute__((ext_vector_type(4)));
typedef unsigned short ushort_t;

__device__ __forceinline__ unsigned short f2bf(float x) {       // round-to-nearest
    union { float f; unsigned u; } v; v.f = x;
    unsigned r = (v.u + 0x7FFFu + ((v.u >> 16) & 1u)) >> 16;
    return (unsigned short)r;
}
__device__ __forceinline__ unsigned short f2bf_trunc(float x) { // truncate mantissa
    union { float f; unsigned u; } v; v.f = x;
    return (unsigned short)(v.u >> 16);
}
__device__ __forceinline__ float bf2f(unsigned short h) {
    union { unsigned u; float f; } v; v.u = ((unsigned)h) << 16;
    return v.f;
}

// ---------------- W split prep: fp32 [1024][64]x3 -> bf16 hi/lo frag layout --
// Wf[((ks*12 + nt)*64 + l)*8 + e], nt: 0-3=Q, 4-7=K, 8-11=V.
// lane l=(c,g): col = (nt&3)*16 + c, k = 32*ks + 8*g + e.
__global__ __launch_bounds__(256) void wsplit_kernel(
    const float* __restrict__ wq, const float* __restrict__ wk,
    const float* __restrict__ wv,
    ushort_t* __restrict__ Wfhi, ushort_t* __restrict__ Wflo)
{
    int tid = blockIdx.x * 256 + threadIdx.x;      // 0..24575
    int l = tid & 63;
    int c = l & 15, g = l >> 4;
    int rest = tid >> 6;
    int nt = rest % 12, ks = rest / 12;
    const float* W = (nt < 4) ? wq : ((nt < 8) ? wk : wv);
    int colm = ((nt & 3) * 16) + c;
    short8 hi, lo;
#pragma unroll
    for (int e = 0; e < 8; ++e) {
        float v = W[(size_t)(32 * ks + 8 * g + e) * HEAD + colm];
        unsigned short h = f2bf_trunc(v);
        hi[e] = (short)h;
        lo[e] = (short)f2bf(v - bf2f(h));
    }
    *(short8*)&Wfhi[(size_t)tid * 8] = hi;
    *(short8*)&Wflo[(size_t)tid * 8] = lo;
}

// ---------------- QKV projection v3: x staged once per block via LDS --------
// Block = 256 thr = 4 waves = one 16-row m-tile; wave w computes nt 3w..3w+2.
// x fp32 -> bf16 hi/lo converted once per element, shared through LDS.
// 8 slabs of 128 k, double-buffered, ONE barrier per slab (write goes to the
// buffer whose last reader was separated by that barrier).
#define KSLAB 128
#define XSTR 132   // LDS row stride in shorts (264 B -> 2-way banks, free)

__global__ __launch_bounds__(256) void proj_kernel(
    const float* __restrict__ x,
    const ushort_t* __restrict__ Wfhi, const ushort_t* __restrict__ Wflo,
    const float* __restrict__ bq, const float* __restrict__ bk,
    const float* __restrict__ bv,
    ushort_t* __restrict__ Qhi, ushort_t* __restrict__ Qlo,
    ushort_t* __restrict__ Khi, ushort_t* __restrict__ Klo,
    ushort_t* __restrict__ Vt)
{
    __shared__ __align__(16) ushort_t xh_lds[2][16][XSTR];
    __shared__ __align__(16) ushort_t xl_lds[2][16][XSTR];
    __shared__ float eld[4][3][16][17];

    const int t = threadIdx.x;
    const int w = t >> 6;
    const int l = t & 63;
    const int c = l & 15, g = l >> 4;
    const int m0 = blockIdx.x * 16;

    // staging mapping: thread t -> row st_r, k-chunk st_k*8 within slab
    const int st_r = t >> 4;
    const int st_k = (t & 15) * 8;
    const float* xbase = &x[(size_t)(m0 + st_r) * D_MODEL + st_k];

    f32x4 acc[3];
#pragma unroll
    for (int j = 0; j < 3; ++j) acc[j] = (f32x4)0.0f;

    // prologue: load + convert + write slab 0
    float4 ra, rb;
    {
        const float* xp = xbase;
        ra = *(const float4*)xp;
        rb = *(const float4*)(xp + 4);
    }
    {
        float xs[8] = {ra.x, ra.y, ra.z, ra.w, rb.x, rb.y, rb.z, rb.w};
        short8 hi, lo;
#pragma unroll
        for (int e = 0; e < 8; ++e) {
            unsigned short h = f2bf_trunc(xs[e]);
            hi[e] = (short)h;
            lo[e] = (short)f2bf(xs[e] - bf2f(h));
        }
        *(short8*)&xh_lds[0][st_r][st_k] = hi;
        *(short8*)&xl_lds[0][st_r][st_k] = lo;
    }

#pragma unroll 1
    for (int s = 0; s < 8; ++s) {
        __syncthreads();
        const int buf = s & 1;
        // issue next slab's global loads early (hide HBM under MFMA)
        if (s < 7) {
            const float* xp = xbase + (s + 1) * KSLAB;
            ra = *(const float4*)xp;
            rb = *(const float4*)(xp + 4);
        }
        // compute this slab: 4 MFMA-k-steps x 3 nt x 3 split-MFMA
#pragma unroll
        for (int ks = 0; ks < 4; ++ks) {
            short8 xh = *(const short8*)&xh_lds[buf][c][ks * 32 + 8 * g];
            short8 xl = *(const short8*)&xl_lds[buf][c][ks * 32 + 8 * g];
            const size_t kg = (size_t)(s * 4 + ks) * 6144;
#pragma unroll
            for (int j = 0; j < 3; ++j) {
                const size_t wo = kg + (size_t)((3 * w + j) * 64 + l) * 8;
                short8 wh = *(const short8*)&Wfhi[wo];
                short8 wl_ = *(const short8*)&Wflo[wo];
                acc[j] = __builtin_amdgcn_mfma_f32_16x16x32_bf16(xh, wh, acc[j], 0, 0, 0);
                acc[j] = __builtin_amdgcn_mfma_f32_16x16x32_bf16(xl, wh, acc[j], 0, 0, 0);
                acc[j] = __builtin_amdgcn_mfma_f32_16x16x32_bf16(xh, wl_, acc[j], 0, 0, 0);
            }
        }
        // convert + write next slab into the other buffer (its last reader
        // was compute(s-1), separated by this iteration's barrier)
        if (s < 7) {
            float xs[8] = {ra.x, ra.y, ra.z, ra.w, rb.x, rb.y, rb.z, rb.w};
            short8 hi, lo;
#pragma unroll
            for (int e = 0; e < 8; ++e) {
                unsigned short h = f2bf_trunc(xs[e]);
                hi[e] = (short)h;
                lo[e] = (short)f2bf(xs[e] - bf2f(h));
            }
            *(short8*)&xh_lds[buf ^ 1][st_r][st_k] = hi;
            *(short8*)&xl_lds[buf ^ 1][st_r][st_k] = lo;
        }
    }

    // epilogue: per-wave LDS regions, no barrier needed
#pragma unroll
    for (int j = 0; j < 3; ++j)
#pragma unroll
        for (int r = 0; r < 4; ++r)
            eld[w][j][4 * g + r][c] = acc[j][r];

    const int b = m0 >> 11;
    const int s0 = m0 & 2047;

#pragma unroll
    for (int j = 0; j < 3; ++j) {
        const int nt = 3 * w + j;
        const int col16 = (nt & 3) * 16;
        if (nt < 8) {
            // Q or K: row = l>>2, 4 cols at (l&3)*4
            const int row = l >> 2, cc4 = (l & 3) * 4;
            const float* bias = (nt < 4) ? bq : bk;
            const float scale = (nt < 4) ? 8.0f : 1.0f;
            ushort_t* Dhi = (nt < 4) ? Qhi : Khi;
            ushort_t* Dlo = (nt < 4) ? Qlo : Klo;
            unsigned hu[2] = {0, 0}, lu[2] = {0, 0};
#pragma unroll
            for (int i = 0; i < 4; ++i) {
                float v = (eld[w][j][row][cc4 + i] + bias[col16 + cc4 + i]) * scale;
                unsigned short h = f2bf_trunc(v);
                unsigned short lo2 = f2bf(v - bf2f(h));
                hu[i >> 1] |= ((unsigned)h) << ((i & 1) * 16);
                lu[i >> 1] |= ((unsigned)lo2) << ((i & 1) * 16);
            }
            size_t off = (size_t)(m0 + row) * HEAD + col16 + cc4;
            *(uint2*)&Dhi[off] = make_uint2(hu[0], hu[1]);
            *(uint2*)&Dlo[off] = make_uint2(lu[0], lu[1]);
        } else {
            // V -> Vt[b][d][s]: d_local = l>>2, 4 s at (l&3)*4
            const int dl = l >> 2, sg = (l & 3) * 4;
            const float bb = bv[col16 + dl];
            unsigned vu[2] = {0, 0};
#pragma unroll
            for (int i = 0; i < 4; ++i) {
                unsigned short v = f2bf(eld[w][j][sg + i][dl] + bb);
                vu[i >> 1] |= ((unsigned)v) << ((i & 1) * 16);
            }
            *(uint2*)&Vt[((size_t)b * HEAD + col16 + dl) * SEQ + s0 + sg] =
                make_uint2(vu[0], vu[1]);
        }
    }
}

// ---------------- Flash causal attention (MFMA, split-KV, 8 waves) ------
#define NW 8
#define CHUNK 16
#define PSTR 88   // Plds stride in shorts: 176B = 11*16B (aligned, ~2-way banks)

__global__ __launch_bounds__(512) void attn_kernel(
    const ushort_t* __restrict__ Qhi, const ushort_t* __restrict__ Qlo,
    const ushort_t* __restrict__ Khi, const ushort_t* __restrict__ Klo,
    const ushort_t* __restrict__ Vt, float* __restrict__ out)
{
    __shared__ float Po[NW][CHUNK][68];
    __shared__ float Pm[NW][CHUNK];
    __shared__ float Pl[NW][CHUNK];
    __shared__ __align__(16) ushort_t Plds[NW][CHUNK][PSTR];

    const int t = threadIdx.x;
    const int w = t >> 6;
    const int l = t & 63;
    const int b = blockIdx.y;
    const int chunk = (int)gridDim.x - 1 - (int)blockIdx.x;  // biggest first
    const int q0 = chunk * CHUNK;
    const int c = l & 15;
    const int g = l >> 4;

    short8 qhi[2], qlo[2];
    {
        const ushort_t* qbase = &Qhi[(size_t)(b * SEQ + q0 + c) * HEAD];
        const ushort_t* qbasel = &Qlo[(size_t)(b * SEQ + q0 + c) * HEAD];
#pragma unroll
        for (int dc = 0; dc < 2; ++dc) {
            qhi[dc] = *(const short8*)&qbase[dc * 32 + 8 * g];
            qlo[dc] = *(const short8*)&qbasel[dc * 32 + 8 * g];
        }
    }

    f32x4 acc[4];
#pragma unroll
    for (int dt = 0; dt < 4; ++dt) acc[dt] = (f32x4)0.0f;
    float mrun = -1e30f, lsum = 0.f;

    const int ntiles = (q0 + CHUNK + 63) >> 6;
#pragma unroll 1
    for (int tile = w; tile < ntiles; tile += NW) {
        const int c0 = tile * 64;
        int nlive = ((q0 + 15 - c0) >> 4) + 1;
        nlive = nlive > 4 ? 4 : nlive;

        float sc[4][4];
        float pv[4][4];
#pragma unroll
        for (int t4 = 0; t4 < 4; ++t4)
#pragma unroll
            for (int r = 0; r < 4; ++r) pv[t4][r] = 0.f;

        float tmax = -1e30f;
#pragma unroll
        for (int t4 = 0; t4 < 4; ++t4) {
            if (t4 < nlive) {
                f32x4 st = (f32x4)0.0f;
                const size_t krow = (size_t)(b * SEQ + c0 + 16 * t4 + c) * HEAD;
#pragma unroll
                for (int dc = 0; dc < 2; ++dc) {
                    short8 khi = *(const short8*)&Khi[krow + dc * 32 + 8 * g];
                    short8 klo = *(const short8*)&Klo[krow + dc * 32 + 8 * g];
                    st = __builtin_amdgcn_mfma_f32_16x16x32_bf16(khi, qhi[dc], st, 0, 0, 0);
                    st = __builtin_amdgcn_mfma_f32_16x16x32_bf16(khi, qlo[dc], st, 0, 0, 0);
                    st = __builtin_amdgcn_mfma_f32_16x16x32_bf16(klo, qhi[dc], st, 0, 0, 0);
                }
#pragma unroll
                for (int r = 0; r < 4; ++r) {
                    int kv = c0 + 16 * t4 + 4 * g + r;
                    float s = (kv <= q0 + c) ? st[r] : -1e30f;
                    sc[t4][r] = s;
                    tmax = fmaxf(tmax, s);
                }
            }
        }
        tmax = fmaxf(tmax, __shfl_xor(tmax, 16));
        tmax = fmaxf(tmax, __shfl_xor(tmax, 32));
        float newm = fmaxf(mrun, tmax);
        float corr = __expf(mrun - newm);
        mrun = newm;

        float psum = 0.f;
#pragma unroll
        for (int t4 = 0; t4 < 4; ++t4) {
            if (t4 < nlive) {
#pragma unroll
                for (int r = 0; r < 4; ++r) {
                    float pp = __expf(sc[t4][r] - newm);
                    pv[t4][r] = pp;
                    psum += pp;
                }
            }
        }
        psum += __shfl_xor(psum, 16);
        psum += __shfl_xor(psum, 32);
        lsum = lsum * corr + psum;

#pragma unroll
        for (int r = 0; r < 4; ++r) {
            float cq = __shfl(corr, 4 * g + r);
#pragma unroll
            for (int dt = 0; dt < 4; ++dt) acc[dt][r] *= cq;
        }

#pragma unroll
        for (int t4 = 0; t4 < 4; ++t4) {
            uint2 u;
            u.x = (unsigned)f2bf(pv[t4][0]) | ((unsigned)f2bf(pv[t4][1]) << 16);
            u.y = (unsigned)f2bf(pv[t4][2]) | ((unsigned)f2bf(pv[t4][3]) << 16);
            *(uint2*)&Plds[w][c][16 * t4 + 4 * g] = u;
        }

        const int nkvc = (nlive + 1) >> 1;
#pragma unroll
        for (int kvc = 0; kvc < 2; ++kvc) {
            if (kvc < nkvc) {
                short8 pf = *(short8*)&Plds[w][c][kvc * 32 + 8 * g];
#pragma unroll
                for (int dt = 0; dt < 4; ++dt) {
                    const ushort_t* vp =
                        &Vt[((size_t)(b * HEAD) + 16 * dt + c) * SEQ + c0 + kvc * 32 + 8 * g];
                    short8 vf = *(const short8*)vp;
                    acc[dt] = __builtin_amdgcn_mfma_f32_16x16x32_bf16(pf, vf, acc[dt], 0, 0, 0);
                }
            }
        }
    }

    if (g == 0) { Pm[w][c] = mrun; Pl[w][c] = lsum; }
#pragma unroll
    for (int dt = 0; dt < 4; ++dt)
#pragma unroll
        for (int r = 0; r < 4; ++r)
            Po[w][4 * g + r][16 * dt + c] = acc[dt][r];
    __syncthreads();

    if (t < 256) {
        const int mr = t >> 4;
        const int md = (t & 15) * 4;
        float M = Pm[0][mr];
#pragma unroll
        for (int ww = 1; ww < NW; ++ww) M = fmaxf(M, Pm[ww][mr]);
        float L = 0.f;
        float4 O; O.x = O.y = O.z = O.w = 0.f;
#pragma unroll
        for (int ww = 0; ww < NW; ++ww) {
            float f = __expf(Pm[ww][mr] - M);
            L += f * Pl[ww][mr];
            float4 p = *(const float4*)&Po[ww][mr][md];
            O.x += f * p.x; O.y += f * p.y; O.z += f * p.z; O.w += f * p.w;
        }
        float inv = 1.0f / L;
        float4 res; res.x = O.x * inv; res.y = O.y * inv; res.z = O.z * inv; res.w = O.w * inv;
        *(float4*)&out[(size_t)(b * SEQ + q0 + mr) * HEAD + md] = res;
    }
}

extern "C" void kernel_launch(void* const* d_in, const int* in_sizes, int n_in,
                              void* d_out, int out_size, void* d_ws, size_t ws_size,
                              hipStream_t stream) {
    (void)in_sizes; (void)n_in; (void)out_size; (void)ws_size;
    const float* x  = (const float*)d_in[0];
    const float* wq = (const float*)d_in[1];
    const float* bq = (const float*)d_in[2];
    const float* wk = (const float*)d_in[3];
    const float* bk = (const float*)d_in[4];
    const float* wv = (const float*)d_in[5];
    const float* bv = (const float*)d_in[6];
    float* out = (float*)d_out;

    // workspace layout: 5.75 MB total (validated footprint)
    ushort_t* Wfhi = (ushort_t*)d_ws;                        // 384 KB
    ushort_t* Wflo = Wfhi + (size_t)D_MODEL * 192;           // 384 KB
    ushort_t* Qhi  = Wflo + (size_t)D_MODEL * 192;           // 1 MB each
    ushort_t* Qlo  = Qhi + (size_t)M_TOT * HEAD;
    ushort_t* Khi  = Qlo + (size_t)M_TOT * HEAD;
    ushort_t* Klo  = Khi + (size_t)M_TOT * HEAD;
    ushort_t* Vt   = Klo + (size_t)M_TOT * HEAD;             // [B][64][S], 1 MB

    hipLaunchKernelGGL(wsplit_kernel, dim3(96), dim3(256), 0, stream,
                       wq, wk, wv, Wfhi, Wflo);
    hipLaunchKernelGGL(proj_kernel, dim3(M_TOT / 16), dim3(256), 0, stream,
                       x, Wfhi, Wflo, bq, bk, bv, Qhi, Qlo, Khi, Klo, Vt);
    hipLaunchKernelGGL(attn_kernel, dim3(SEQ / CHUNK, BATCH), dim3(512), 0, stream,
                       Qhi, Qlo, Khi, Klo, Vt, out);
}